// Round 2
// baseline (487.802 us; speedup 1.0000x reference)
//
#include <hip/hip_runtime.h>
#include <math.h>

// Problem constants (fixed by reference setup_inputs)
namespace {
constexpr int Bn = 4;     // batch
constexpr int Cn = 64;    // in channels
constexpr int On = 64;    // out channels
constexpr int Hn = 128;
constexpr int Wn = 128;
constexpr int Kn = 9;     // 3x3 taps
constexpr int HWn = Hn * Wn;          // 16384
constexpr int CKn = Cn * Kn;          // 576
constexpr int NPIX = Bn * HWn;        // 65536
}

// ---------------------------------------------------------------------------
// Prep: transpose weights so hot loops read contiguous wave-uniform rows
//   wt   [(c*9+k)*64 + o]  = weight[o*576 + c*9 + k]   (36864 elems)
//   wtoff[(c*9+k)*18 + j]  = w_off [j*576 + c*9 + k]   (10368 elems)
// ---------------------------------------------------------------------------
__global__ __launch_bounds__(256) void prep_transpose(
    const float* __restrict__ w_off, const float* __restrict__ weight,
    float* __restrict__ wtoff, float* __restrict__ wt) {
  int t = blockIdx.x * 256 + threadIdx.x;
  if (t < On * CKn) {
    int o = t & 63, ck = t >> 6;
    wt[t] = weight[o * CKn + ck];
  }
  if (t < 18 * CKn) {
    int j = t % 18, ck = t / 18;
    wtoff[t] = w_off[j * CKn + ck];
  }
}

// ---------------------------------------------------------------------------
// Offset conv: Conv2d(64 -> 18, 3x3, pad 1).
// Block = 256 threads = 64 pixels (lane) x 4 c-chunks (wave index).
// Each wave accumulates 18 partial sums over its 16 channels; LDS reduce.
// Grid = 1024 blocks -> 4 waves/SIMD.
// offset layout written: [B][18][H][W] (channel 2k = dy_k, 2k+1 = dx_k)
// ---------------------------------------------------------------------------
__global__ __launch_bounds__(256) void offset_conv(
    const float* __restrict__ x, const float* __restrict__ wtoff,
    const float* __restrict__ b_off, float* __restrict__ offset) {
  __shared__ float red[4][18][72];  // +8 pad, conflict-free

  const int lane = threadIdx.x & 63;
  const int wavi = threadIdx.x >> 6;
  const int pixbase = blockIdx.x * 64;       // 64 consecutive px (same b,y)
  const int pix = pixbase + lane;
  const int b = pix >> 14;
  const int rem = pix & (HWn - 1);
  const int y = rem >> 7;
  const int xx = rem & (Wn - 1);

  float acc[18];
#pragma unroll
  for (int j = 0; j < 18; ++j) acc[j] = 0.f;

  const float* xb = x + (size_t)b * Cn * HWn;
  const int c0 = wavi * 16;
  for (int c = c0; c < c0 + 16; ++c) {
    const float* plane = xb + c * HWn;
    const float* wrow = wtoff + c * (Kn * 18);
#pragma unroll
    for (int k = 0; k < Kn; ++k) {
      const int dy = k / 3 - 1, dx = k % 3 - 1;
      int yy = y + dy, xc = xx + dx;
      float v = 0.f;
      if (yy >= 0 && yy < Hn && xc >= 0 && xc < Wn) v = plane[yy * Wn + xc];
#pragma unroll
      for (int j = 0; j < 18; ++j) acc[j] = fmaf(v, wrow[k * 18 + j], acc[j]);
    }
  }

#pragma unroll
  for (int j = 0; j < 18; ++j) red[wavi][j][lane] = acc[j];
  __syncthreads();

  // reduce 4 partials; 18*64 = 1152 outputs / 256 threads
  const int by = pixbase & (HWn - 1);  // base offset within the image
  const int bb = pixbase >> 14;
  float* ob = offset + (size_t)bb * 18 * HWn;
  for (int idx = threadIdx.x; idx < 18 * 64; idx += 256) {
    int j = idx >> 6, l2 = idx & 63;
    float s = red[0][j][l2] + red[1][j][l2] + red[2][j][l2] + red[3][j][l2] +
              b_off[j];
    ob[j * HWn + by + l2] = s;  // coalesced across l2
  }
}

// ---------------------------------------------------------------------------
// Main DCN. Block = 256 threads = 256 pixels; blockIdx encodes (pixblock,
// o-chunk). Each thread: 16 output accumulators over o in [16*oc, 16*oc+16).
// k outer (tap params in regs), c inner: 1 bilinear sample + 16 FMAs
// against scalar-loaded weight row. Grid = 1024 blocks -> 4 waves/SIMD.
// ---------------------------------------------------------------------------
__global__ __launch_bounds__(256) void dcn_main(
    const float* __restrict__ x, const float* __restrict__ offset,
    const float* __restrict__ wt, float* __restrict__ out) {
  const int oc = blockIdx.x & 3;            // o-chunk
  const int pix = (blockIdx.x >> 2) * 256 + threadIdx.x;
  const int b = pix >> 14;
  const int rem = pix & (HWn - 1);
  const int y = rem >> 7;
  const int xx = rem & (Wn - 1);

  const float* xb = x + (size_t)b * Cn * HWn;
  const float* offb = offset + (size_t)b * 18 * HWn + y * Wn + xx;

  float acc[16];
#pragma unroll
  for (int o = 0; o < 16; ++o) acc[o] = 0.f;

#pragma unroll
  for (int k = 0; k < Kn; ++k) {
    const int dy = k / 3 - 1, dx = k % 3 - 1;
    float py = (float)(y + dy) + offb[(2 * k) * HWn];
    float px = (float)(xx + dx) + offb[(2 * k + 1) * HWn];

    float y0f = floorf(py), x0f = floorf(px);
    int y0 = (int)y0f, x0 = (int)x0f;
    int y1 = y0 + 1, x1 = x0 + 1;
    float wy1 = py - y0f, wx1 = px - x0f;
    float wy0 = 1.f - wy1, wx0 = 1.f - wx1;

    // validity masks folded into the bilinear weights
    float my0 = (y0 >= 0 && y0 < Hn) ? 1.f : 0.f;
    float my1 = (y1 >= 0 && y1 < Hn) ? 1.f : 0.f;
    float mx0 = (x0 >= 0 && x0 < Wn) ? 1.f : 0.f;
    float mx1 = (x1 >= 0 && x1 < Wn) ? 1.f : 0.f;
    float w00 = wy0 * wx0 * my0 * mx0;
    float w01 = wy0 * wx1 * my0 * mx1;
    float w10 = wy1 * wx0 * my1 * mx0;
    float w11 = wy1 * wx1 * my1 * mx1;

    // clamped linear offsets (masked corners read a valid addr, weight 0)
    int cy0 = min(max(y0, 0), Hn - 1), cy1 = min(max(y1, 0), Hn - 1);
    int cx0 = min(max(x0, 0), Wn - 1), cx1 = min(max(x1, 0), Wn - 1);
    int l00 = cy0 * Wn + cx0, l01 = cy0 * Wn + cx1;
    int l10 = cy1 * Wn + cx0, l11 = cy1 * Wn + cx1;

    const float* wbase = wt + k * 64 + oc * 16;
    for (int c = 0; c < Cn; ++c) {
      const float* plane = xb + c * HWn;
      float v = w00 * plane[l00] + w01 * plane[l01] +
                w10 * plane[l10] + w11 * plane[l11];
      const float* wr = wbase + c * (Kn * 64);  // wave-uniform -> s_load
#pragma unroll
      for (int o = 0; o < 16; ++o) acc[o] = fmaf(v, wr[o], acc[o]);
    }
  }

  float* ob = out + (size_t)b * On * HWn + (oc * 16) * HWn + y * Wn + xx;
#pragma unroll
  for (int o = 0; o < 16; ++o) ob[o * HWn] = acc[o];  // coalesced per o
}

// ---------------------------------------------------------------------------
extern "C" void kernel_launch(void* const* d_in, const int* in_sizes, int n_in,
                              void* d_out, int out_size, void* d_ws, size_t ws_size,
                              hipStream_t stream) {
  const float* x = (const float*)d_in[0];       // [4,64,128,128]
  const float* w_off = (const float*)d_in[1];   // [18,64,3,3]
  const float* b_off = (const float*)d_in[2];   // [18]
  const float* weight = (const float*)d_in[3];  // [64,64,3,3]
  float* out = (float*)d_out;                   // [4,64,128,128]

  // workspace layout (floats)
  float* offset = (float*)d_ws;                 // 4*18*16384 = 1,179,648
  float* wt = offset + (size_t)Bn * 18 * HWn;   // 36,864
  float* wtoff = wt + On * CKn;                 // 10,368

  {
    int n = On * CKn;  // 36864 covers both transposes
    prep_transpose<<<dim3((n + 255) / 256), dim3(256), 0, stream>>>(
        w_off, weight, wtoff, wt);
  }
  offset_conv<<<dim3(NPIX / 64), dim3(256), 0, stream>>>(x, wtoff, b_off,
                                                         offset);
  dcn_main<<<dim3((NPIX / 256) * 4), dim3(256), 0, stream>>>(x, offset, wt,
                                                             out);
}

// Round 3
// 188.711 us; speedup vs baseline: 2.5849x; 2.5849x over previous
//
#include <hip/hip_runtime.h>
#include <math.h>

typedef _Float16 f16;
typedef _Float16 f16x8 __attribute__((ext_vector_type(8)));
typedef float f32x4 __attribute__((ext_vector_type(4)));

// Problem constants (fixed by reference setup_inputs)
namespace {
constexpr int Bn = 4;     // batch
constexpr int Cn = 64;    // in channels
constexpr int On = 64;    // out channels
constexpr int Hn = 128;
constexpr int Wn = 128;
constexpr int Kn = 9;     // 3x3 taps
constexpr int HWn = Hn * Wn;          // 16384
constexpr int CKn = Cn * Kn;          // 576
constexpr int NPIX = Bn * HWn;        // 65536
constexpr int SR = 72;                // padded LDS row stride (halves): 64+8
}

// ---------------------------------------------------------------------------
// Prep weights:
//   wtoff[(c*9+k)*18 + j] = w_off[j*576 + c*9 + k]      (10368 f32)
//   wtb  [(k*64+o)*64+c]  = (f16) weight[(o*64+c)*9+k]  (36864 f16)
// ---------------------------------------------------------------------------
__global__ __launch_bounds__(256) void prep_weights(
    const float* __restrict__ w_off, const float* __restrict__ weight,
    float* __restrict__ wtoff, f16* __restrict__ wtb) {
  int t = blockIdx.x * 256 + threadIdx.x;
  if (t < Kn * On * Cn) {  // 36864
    int c = t & 63, o = (t >> 6) & 63, k = t >> 12;
    wtb[t] = (f16)weight[((o << 6) + c) * 9 + k];
  }
  if (t < 18 * CKn) {
    int j = t % 18, ck = t / 18;
    wtoff[t] = w_off[j * CKn + ck];
  }
}

// ---------------------------------------------------------------------------
// Transpose x [B][C][H][W] f32 -> xt [B][H*W][C] f16 (channels-last).
// Block = 64 hw positions x 64 channels; thread t: lane=t&63 (hw),
// cw=t>>6 (16-channel chunk). Reads coalesced across lanes; writes 2x16B.
// ---------------------------------------------------------------------------
__global__ __launch_bounds__(256) void transpose_x(
    const float* __restrict__ x, f16* __restrict__ xt) {
  const int l = threadIdx.x & 63;
  const int cw = threadIdx.x >> 6;          // 0..3
  const int pixbase = blockIdx.x * 64;
  const int b = pixbase >> 14;
  const int hw = (pixbase & (HWn - 1)) + l;

  f16x8 v0, v1;
#pragma unroll
  for (int i = 0; i < 8; ++i) {
    v0[i] = (f16)x[((size_t)(b * Cn + cw * 16 + i)) * HWn + hw];
    v1[i] = (f16)x[((size_t)(b * Cn + cw * 16 + 8 + i)) * HWn + hw];
  }
  f16* dst = xt + ((size_t)(b * HWn + hw)) * 64 + cw * 16;
  *(f16x8*)dst = v0;
  *(f16x8*)(dst + 8) = v1;
}

// ---------------------------------------------------------------------------
// Offset conv: Conv2d(64 -> 18, 3x3, pad 1).
// Block = 256 threads = 64 pixels (lane) x 4 c-chunks (wave index).
// Output layout: [B][HW][18] (per-pixel contiguous) for the main kernel.
// ---------------------------------------------------------------------------
__global__ __launch_bounds__(256) void offset_conv(
    const float* __restrict__ x, const float* __restrict__ wtoff,
    const float* __restrict__ b_off, float* __restrict__ offset) {
  __shared__ float red[4][18][72];  // +8 pad

  const int lane = threadIdx.x & 63;
  const int wavi = threadIdx.x >> 6;
  const int pixbase = blockIdx.x * 64;  // 64 consecutive px (same b,y)
  const int pix = pixbase + lane;
  const int b = pix >> 14;
  const int rem = pix & (HWn - 1);
  const int y = rem >> 7;
  const int xx = rem & (Wn - 1);

  float acc[18];
#pragma unroll
  for (int j = 0; j < 18; ++j) acc[j] = 0.f;

  const float* xb = x + (size_t)b * Cn * HWn;
  const int c0 = wavi * 16;
  for (int c = c0; c < c0 + 16; ++c) {
    const float* plane = xb + c * HWn;
    const float* wrow = wtoff + c * (Kn * 18);
#pragma unroll
    for (int k = 0; k < Kn; ++k) {
      const int dy = k / 3 - 1, dx = k % 3 - 1;
      int yy = y + dy, xc = xx + dx;
      float v = 0.f;
      if (yy >= 0 && yy < Hn && xc >= 0 && xc < Wn) v = plane[yy * Wn + xc];
#pragma unroll
      for (int j = 0; j < 18; ++j) acc[j] = fmaf(v, wrow[k * 18 + j], acc[j]);
    }
  }

#pragma unroll
  for (int j = 0; j < 18; ++j) red[wavi][j][lane] = acc[j];
  __syncthreads();

  const int by = pixbase & (HWn - 1);
  const int bb = pixbase >> 14;
  float* ob = offset + (size_t)bb * HWn * 18;
  for (int idx = threadIdx.x; idx < 18 * 64; idx += 256) {
    int j = idx >> 6, l2 = idx & 63;
    float s = red[0][j][l2] + red[1][j][l2] + red[2][j][l2] + red[3][j][l2] +
              b_off[j];
    ob[(size_t)(by + l2) * 18 + j] = s;
  }
}

// ---------------------------------------------------------------------------
// Main DCN as MFMA GEMM. Block = 256 thr (4 waves) handles 64 consecutive px.
// Per tap k: sample S_k[64px][64c] (f16, LDS) from channels-last xt,
// stage W_k[64o][64c] (f16, LDS), then 4 waves do C[64o][64px] += W_k*S_k
// via v_mfma_f32_16x16x32_f16 (wave w: o in [16w,16w+16), all 64 px,
// acc = 4 x float4). Double-buffered, 1 barrier per tap.
// ---------------------------------------------------------------------------
__global__ __launch_bounds__(256, 4) void dcn_main(
    const f16* __restrict__ xt, const float* __restrict__ offset,
    const f16* __restrict__ wtb, float* __restrict__ out) {
  __shared__ __align__(16) f16 Sb[2][64 * SR];
  __shared__ __align__(16) f16 Wb[2][64 * SR];

  const int t = threadIdx.x;
  const int px_s = t >> 2, cq = t & 3;      // sampling role
  const int pxg = blockIdx.x * 64 + px_s;
  const int b = pxg >> 14;
  const int rem = pxg & (HWn - 1);
  const int y = rem >> 7;
  const int xx = rem & (Wn - 1);
  const f16* xb = xt + (((size_t)b) << 14) * 64;

  const int lane = t & 63, wv = t >> 6;     // gemm role
  const int l15 = lane & 15, q = lane >> 4;
  const int obase = wv * 16;

  auto stage = [&](int k, int buf) {
    const int dy = k / 3 - 1, dx = k % 3 - 1;
    float2 o2 = *(const float2*)(offset + (size_t)pxg * 18 + 2 * k);
    float py = (float)(y + dy) + o2.x;
    float pxf = (float)(xx + dx) + o2.y;
    float y0f = floorf(py), x0f = floorf(pxf);
    int y0 = (int)y0f, x0 = (int)x0f;
    int y1 = y0 + 1, x1 = x0 + 1;
    float wy1 = py - y0f, wx1 = pxf - x0f;
    float wy0 = 1.f - wy1, wx0 = 1.f - wx1;
    float my0 = (y0 >= 0 && y0 < Hn) ? 1.f : 0.f;
    float my1 = (y1 >= 0 && y1 < Hn) ? 1.f : 0.f;
    float mx0 = (x0 >= 0 && x0 < Wn) ? 1.f : 0.f;
    float mx1 = (x1 >= 0 && x1 < Wn) ? 1.f : 0.f;
    float w00 = wy0 * wx0 * my0 * mx0;
    float w01 = wy0 * wx1 * my0 * mx1;
    float w10 = wy1 * wx0 * my1 * mx0;
    float w11 = wy1 * wx1 * my1 * mx1;
    int cy0 = min(max(y0, 0), Hn - 1), cy1 = min(max(y1, 0), Hn - 1);
    int cx0 = min(max(x0, 0), Wn - 1), cx1 = min(max(x1, 0), Wn - 1);
    const f16* r00 = xb + (size_t)(cy0 * Wn + cx0) * 64 + cq * 16;
    const f16* r01 = xb + (size_t)(cy0 * Wn + cx1) * 64 + cq * 16;
    const f16* r10 = xb + (size_t)(cy1 * Wn + cx0) * 64 + cq * 16;
    const f16* r11 = xb + (size_t)(cy1 * Wn + cx1) * 64 + cq * 16;
    f16* sdst = &Sb[buf][px_s * SR + cq * 16];
#pragma unroll
    for (int h = 0; h < 2; ++h) {
      f16x8 a = *(const f16x8*)(r00 + h * 8);
      f16x8 bb2 = *(const f16x8*)(r01 + h * 8);
      f16x8 c = *(const f16x8*)(r10 + h * 8);
      f16x8 d = *(const f16x8*)(r11 + h * 8);
      f16x8 v;
#pragma unroll
      for (int i = 0; i < 8; ++i) {
        float s = w00 * (float)a[i] + w01 * (float)bb2[i] +
                  w10 * (float)c[i] + w11 * (float)d[i];
        v[i] = (f16)s;
      }
      *(f16x8*)(sdst + h * 8) = v;
    }
    // W_k staging: thread copies 32 B (o = t>>2, quarter-row = t&3)
    {
      const int o = t >> 2, part = t & 3;
      const f16* src = wtb + (((size_t)(k * 64 + o)) << 6) + part * 16;
      f16* dst = &Wb[buf][o * SR + part * 16];
      *(f16x8*)dst = *(const f16x8*)src;
      *(f16x8*)(dst + 8) = *(const f16x8*)(src + 8);
    }
  };

  f32x4 acc[4];
#pragma unroll
  for (int pt = 0; pt < 4; ++pt) acc[pt] = (f32x4){0.f, 0.f, 0.f, 0.f};

  stage(0, 0);
  __syncthreads();
  for (int k = 0; k < Kn; ++k) {
    const int cur = k & 1;
    if (k + 1 < Kn) stage(k + 1, 1 - cur);
#pragma unroll
    for (int s = 0; s < 2; ++s) {
      f16x8 af = *(const f16x8*)&Wb[cur][(obase + l15) * SR + s * 32 + q * 8];
#pragma unroll
      for (int pt = 0; pt < 4; ++pt) {
        f16x8 bf =
            *(const f16x8*)&Sb[cur][(pt * 16 + l15) * SR + s * 32 + q * 8];
        acc[pt] = __builtin_amdgcn_mfma_f32_16x16x32_f16(af, bf, acc[pt],
                                                         0, 0, 0);
      }
    }
    __syncthreads();
  }

  // Epilogue: C/D layout col=lane&15 (px), row=q*4+reg (o within wave chunk)
  const int hw0 = (blockIdx.x * 64) & (HWn - 1);
  const int bb = (blockIdx.x * 64) >> 14;
  float* ob = out + (size_t)bb * On * HWn + hw0;
#pragma unroll
  for (int pt = 0; pt < 4; ++pt) {
#pragma unroll
    for (int r = 0; r < 4; ++r) {
      int o = obase + q * 4 + r;
      ob[(size_t)o * HWn + pt * 16 + l15] = acc[pt][r];
    }
  }
}

// ---------------------------------------------------------------------------
extern "C" void kernel_launch(void* const* d_in, const int* in_sizes, int n_in,
                              void* d_out, int out_size, void* d_ws, size_t ws_size,
                              hipStream_t stream) {
  const float* x = (const float*)d_in[0];       // [4,64,128,128]
  const float* w_off = (const float*)d_in[1];   // [18,64,3,3]
  const float* b_off = (const float*)d_in[2];   // [18]
  const float* weight = (const float*)d_in[3];  // [64,64,3,3]
  float* out = (float*)d_out;                   // [4,64,128,128]

  // workspace layout
  f16* xt = (f16*)d_ws;                          // 4,194,304 f16 = 8 MB
  float* offset = (float*)(xt + (size_t)NPIX * Cn);  // 1,179,648 f32 = 4.5 MB
  float* wtoff = offset + (size_t)NPIX * 18;     // 10,368 f32
  f16* wtb = (f16*)(wtoff + 18 * CKn);           // 36,864 f16

  prep_weights<<<dim3(144), dim3(256), 0, stream>>>(w_off, weight, wtoff, wtb);
  transpose_x<<<dim3(NPIX / 64), dim3(256), 0, stream>>>(x, xt);
  offset_conv<<<dim3(NPIX / 64), dim3(256), 0, stream>>>(x, wtoff, b_off,
                                                         offset);
  dcn_main<<<dim3(NPIX / 64), dim3(256), 0, stream>>>(xt, offset, wtb, out);
}

// Round 4
// 111.795 us; speedup vs baseline: 4.3634x; 1.6880x over previous
//
#include <hip/hip_runtime.h>
#include <math.h>

typedef _Float16 f16;
typedef _Float16 f16x8 __attribute__((ext_vector_type(8)));
typedef float f32x4 __attribute__((ext_vector_type(4)));

// Problem constants (fixed by reference setup_inputs)
namespace {
constexpr int Bn = 4;     // batch
constexpr int Cn = 64;    // in channels
constexpr int On = 64;    // out channels
constexpr int Hn = 128;
constexpr int Wn = 128;
constexpr int Kn = 9;     // 3x3 taps
constexpr int HWn = Hn * Wn;          // 16384
constexpr int CKn = Cn * Kn;          // 576
constexpr int NPIX = Bn * HWn;        // 65536
constexpr int SR = 72;                // padded LDS row stride (halves): 64+8
}

// ---------------------------------------------------------------------------
// Prep weights (f16, MFMA-ready layouts):
//   wtb [(k*64+o)*64+c] = (f16) weight[(o*64+c)*9+k]   (36864 f16)
//   wofb[(k*32+o)*64+c] = (f16) w_off [(o*64+c)*9+k]   (o<18, else 0; 18432)
// ---------------------------------------------------------------------------
__global__ __launch_bounds__(256) void prep_weights(
    const float* __restrict__ w_off, const float* __restrict__ weight,
    f16* __restrict__ wofb, f16* __restrict__ wtb) {
  int t = blockIdx.x * 256 + threadIdx.x;
  if (t < Kn * On * Cn) {  // 36864
    int c = t & 63, o = (t >> 6) & 63, k = t >> 12;
    wtb[t] = (f16)weight[((o << 6) + c) * 9 + k];
  }
  if (t < Kn * 32 * Cn) {  // 18432
    int c = t & 63, o = (t >> 6) & 31, k = t >> 11;
    float v = (o < 18) ? w_off[((o << 6) + c) * 9 + k] : 0.f;
    wofb[t] = (f16)v;
  }
}

// ---------------------------------------------------------------------------
// Transpose x [B][C][H][W] f32 -> xt [B][H*W][C] f16 (channels-last).
// ---------------------------------------------------------------------------
__global__ __launch_bounds__(256) void transpose_x(
    const float* __restrict__ x, f16* __restrict__ xt) {
  const int l = threadIdx.x & 63;
  const int cw = threadIdx.x >> 6;          // 0..3
  const int pixbase = blockIdx.x * 64;
  const int b = pixbase >> 14;
  const int hw = (pixbase & (HWn - 1)) + l;

  f16x8 v0, v1;
#pragma unroll
  for (int i = 0; i < 8; ++i) {
    v0[i] = (f16)x[((size_t)(b * Cn + cw * 16 + i)) * HWn + hw];
    v1[i] = (f16)x[((size_t)(b * Cn + cw * 16 + 8 + i)) * HWn + hw];
  }
  f16* dst = xt + ((size_t)(b * HWn + hw)) * 64 + cw * 16;
  *(f16x8*)dst = v0;
  *(f16x8*)(dst + 8) = v1;
}

// ---------------------------------------------------------------------------
// Offset conv as MFMA GEMM: offset[px][18] = Woff[18][576] x im2col[576][px].
// Same skeleton as dcn_main: block = 64 px (half row, same b,y), 4 waves.
// Per tap k: stage S_k[64px][64c] from xt (integer shift, zero-pad border),
// stage Woff_k[32 o][64 c], then 2 M-tiles x 4 N-tiles of 16x16x32 f16 MFMA
// split over 4 waves (wave w: m = w&1, n in {2*(w>>1), 2*(w>>1)+1}).
// Epilogue adds bias, stores o<18 to offset [B][HW][18] (f32).
// ---------------------------------------------------------------------------
__global__ __launch_bounds__(256) void offset_mfma(
    const f16* __restrict__ xt, const f16* __restrict__ wofb,
    const float* __restrict__ b_off, float* __restrict__ offset) {
  __shared__ __align__(16) f16 Sb[2][64 * SR];   // 18432 B
  __shared__ __align__(16) f16 Wb[2][32 * SR];   //  9216 B

  const int t = threadIdx.x;
  const int pixbase = blockIdx.x * 64;
  const int b = pixbase >> 14;
  const int y = (pixbase & (HWn - 1)) >> 7;
  const int xx0 = pixbase & (Wn - 1);            // 0 or 64
  const f16* xb = xt + ((size_t)b * HWn) * 64;

  const int px_s = t >> 2, cq = t & 3;           // S-staging role
  const int lane = t & 63, wv = t >> 6;          // gemm role
  const int l15 = lane & 15, q = lane >> 4;
  const int m = wv & 1;                          // o-tile (0..1)
  const int nb = (wv >> 1) * 2;                  // first n-tile (0 or 2)

  auto stage = [&](int k, int buf) {
    const int dy = k / 3 - 1, dx = k % 3 - 1;
    const int ys = y + dy, xs = xx0 + px_s + dx;
    f16* sdst = &Sb[buf][px_s * SR + cq * 16];
    if (ys >= 0 && ys < Hn && xs >= 0 && xs < Wn) {
      const f16* src = xb + (size_t)(ys * Wn + xs) * 64 + cq * 16;
      *(f16x8*)sdst = *(const f16x8*)src;
      *(f16x8*)(sdst + 8) = *(const f16x8*)(src + 8);
    } else {
      f16x8 z = {};
      *(f16x8*)sdst = z;
      *(f16x8*)(sdst + 8) = z;
    }
    // Woff_k staging: 32 rows x 64 c; thread copies 16 B
    const int o = t >> 3, part = t & 7;
    const f16* wsrc = wofb + (((size_t)(k * 32 + o)) << 6) + part * 8;
    *(f16x8*)&Wb[buf][o * SR + part * 8] = *(const f16x8*)wsrc;
  };

  f32x4 acc[2];
#pragma unroll
  for (int t2 = 0; t2 < 2; ++t2) acc[t2] = (f32x4){0.f, 0.f, 0.f, 0.f};

  stage(0, 0);
  __syncthreads();
  for (int k = 0; k < Kn; ++k) {
    const int cur = k & 1;
    if (k + 1 < Kn) stage(k + 1, 1 - cur);
#pragma unroll
    for (int s = 0; s < 2; ++s) {
      f16x8 af = *(const f16x8*)&Wb[cur][(m * 16 + l15) * SR + s * 32 + q * 8];
#pragma unroll
      for (int t2 = 0; t2 < 2; ++t2) {
        f16x8 bf = *(const f16x8*)
            &Sb[cur][((nb + t2) * 16 + l15) * SR + s * 32 + q * 8];
        acc[t2] = __builtin_amdgcn_mfma_f32_16x16x32_f16(af, bf, acc[t2],
                                                         0, 0, 0);
      }
    }
    __syncthreads();
  }

  // Epilogue: C/D col=lane&15 (px within n-tile), row=q*4+r (o within m-tile)
  float* ob = offset + ((size_t)b * HWn + y * Wn + xx0) * 18;
#pragma unroll
  for (int t2 = 0; t2 < 2; ++t2) {
#pragma unroll
    for (int r = 0; r < 4; ++r) {
      int o = m * 16 + q * 4 + r;
      if (o < 18) {
        int pxl = (nb + t2) * 16 + l15;
        ob[(size_t)pxl * 18 + o] = acc[t2][r] + b_off[o];
      }
    }
  }
}

// ---------------------------------------------------------------------------
// Main DCN as MFMA GEMM. Block = 256 thr (4 waves) handles 64 consecutive px.
// Per tap k: sample S_k[64px][64c] (f16, LDS) from channels-last xt,
// stage W_k[64o][64c] (f16, LDS), then 4 waves do C[64o][64px] += W_k*S_k
// via v_mfma_f32_16x16x32_f16. Double-buffered, 1 barrier per tap.
// All 9 per-pixel offset pairs preloaded to registers up front.
// ---------------------------------------------------------------------------
__global__ __launch_bounds__(256, 4) void dcn_main(
    const f16* __restrict__ xt, const float* __restrict__ offset,
    const f16* __restrict__ wtb, float* __restrict__ out) {
  __shared__ __align__(16) f16 Sb[2][64 * SR];
  __shared__ __align__(16) f16 Wb[2][64 * SR];

  const int t = threadIdx.x;
  const int px_s = t >> 2, cq = t & 3;      // sampling role
  const int pxg = blockIdx.x * 64 + px_s;
  const int b = pxg >> 14;
  const int rem = pxg & (HWn - 1);
  const int y = rem >> 7;
  const int xx = rem & (Wn - 1);
  const f16* xb = xt + (((size_t)b) << 14) * 64;

  const int lane = t & 63, wv = t >> 6;     // gemm role
  const int l15 = lane & 15, q = lane >> 4;
  const int obase = wv * 16;

  // preload all 9 offset pairs (18 contiguous floats)
  float2 off9[9];
  {
    const float* ofp = offset + (size_t)pxg * 18;
#pragma unroll
    for (int k = 0; k < Kn; ++k) off9[k] = *(const float2*)(ofp + 2 * k);
  }

  auto stage = [&](int k, int buf) {
    const int dy = k / 3 - 1, dx = k % 3 - 1;
    float py = (float)(y + dy) + off9[k].x;
    float pxf = (float)(xx + dx) + off9[k].y;
    float y0f = floorf(py), x0f = floorf(pxf);
    int y0 = (int)y0f, x0 = (int)x0f;
    int y1 = y0 + 1, x1 = x0 + 1;
    float wy1 = py - y0f, wx1 = pxf - x0f;
    float wy0 = 1.f - wy1, wx0 = 1.f - wx1;
    float my0 = (y0 >= 0 && y0 < Hn) ? 1.f : 0.f;
    float my1 = (y1 >= 0 && y1 < Hn) ? 1.f : 0.f;
    float mx0 = (x0 >= 0 && x0 < Wn) ? 1.f : 0.f;
    float mx1 = (x1 >= 0 && x1 < Wn) ? 1.f : 0.f;
    float w00 = wy0 * wx0 * my0 * mx0;
    float w01 = wy0 * wx1 * my0 * mx1;
    float w10 = wy1 * wx0 * my1 * mx0;
    float w11 = wy1 * wx1 * my1 * mx1;
    int cy0 = min(max(y0, 0), Hn - 1), cy1 = min(max(y1, 0), Hn - 1);
    int cx0 = min(max(x0, 0), Wn - 1), cx1 = min(max(x1, 0), Wn - 1);
    const f16* r00 = xb + (size_t)(cy0 * Wn + cx0) * 64 + cq * 16;
    const f16* r01 = xb + (size_t)(cy0 * Wn + cx1) * 64 + cq * 16;
    const f16* r10 = xb + (size_t)(cy1 * Wn + cx0) * 64 + cq * 16;
    const f16* r11 = xb + (size_t)(cy1 * Wn + cx1) * 64 + cq * 16;
    f16* sdst = &Sb[buf][px_s * SR + cq * 16];
#pragma unroll
    for (int h = 0; h < 2; ++h) {
      f16x8 a = *(const f16x8*)(r00 + h * 8);
      f16x8 bb2 = *(const f16x8*)(r01 + h * 8);
      f16x8 c = *(const f16x8*)(r10 + h * 8);
      f16x8 d = *(const f16x8*)(r11 + h * 8);
      f16x8 v;
#pragma unroll
      for (int i = 0; i < 8; ++i) {
        float s = w00 * (float)a[i] + w01 * (float)bb2[i] +
                  w10 * (float)c[i] + w11 * (float)d[i];
        v[i] = (f16)s;
      }
      *(f16x8*)(sdst + h * 8) = v;
    }
    // W_k staging: thread copies 32 B (o = t>>2, quarter-row = t&3)
    {
      const int o = t >> 2, part = t & 3;
      const f16* src = wtb + (((size_t)(k * 64 + o)) << 6) + part * 16;
      f16* dst = &Wb[buf][o * SR + part * 16];
      *(f16x8*)dst = *(const f16x8*)src;
      *(f16x8*)(dst + 8) = *(const f16x8*)(src + 8);
    }
  };

  f32x4 acc[4];
#pragma unroll
  for (int pt = 0; pt < 4; ++pt) acc[pt] = (f32x4){0.f, 0.f, 0.f, 0.f};

  stage(0, 0);
  __syncthreads();
  for (int k = 0; k < Kn; ++k) {
    const int cur = k & 1;
    if (k + 1 < Kn) stage(k + 1, 1 - cur);
#pragma unroll
    for (int s = 0; s < 2; ++s) {
      f16x8 af = *(const f16x8*)&Wb[cur][(obase + l15) * SR + s * 32 + q * 8];
#pragma unroll
      for (int pt = 0; pt < 4; ++pt) {
        f16x8 bf =
            *(const f16x8*)&Sb[cur][(pt * 16 + l15) * SR + s * 32 + q * 8];
        acc[pt] = __builtin_amdgcn_mfma_f32_16x16x32_f16(af, bf, acc[pt],
                                                         0, 0, 0);
      }
    }
    __syncthreads();
  }

  // Epilogue: C/D layout col=lane&15 (px), row=q*4+reg (o within wave chunk)
  const int hw0 = (blockIdx.x * 64) & (HWn - 1);
  const int bb = (blockIdx.x * 64) >> 14;
  float* ob = out + (size_t)bb * On * HWn + hw0;
#pragma unroll
  for (int pt = 0; pt < 4; ++pt) {
#pragma unroll
    for (int r = 0; r < 4; ++r) {
      int o = obase + q * 4 + r;
      ob[(size_t)o * HWn + pt * 16 + l15] = acc[pt][r];
    }
  }
}

// ---------------------------------------------------------------------------
extern "C" void kernel_launch(void* const* d_in, const int* in_sizes, int n_in,
                              void* d_out, int out_size, void* d_ws, size_t ws_size,
                              hipStream_t stream) {
  const float* x = (const float*)d_in[0];       // [4,64,128,128]
  const float* w_off = (const float*)d_in[1];   // [18,64,3,3]
  const float* b_off = (const float*)d_in[2];   // [18]
  const float* weight = (const float*)d_in[3];  // [64,64,3,3]
  float* out = (float*)d_out;                   // [4,64,128,128]

  // workspace layout
  f16* xt = (f16*)d_ws;                              // 4,194,304 f16 = 8 MB
  float* offset = (float*)(xt + (size_t)NPIX * Cn);  // 1,179,648 f32
  f16* wtb = (f16*)(offset + (size_t)NPIX * 18);     // 36,864 f16
  f16* wofb = wtb + Kn * On * Cn;                    // 18,432 f16

  prep_weights<<<dim3(144), dim3(256), 0, stream>>>(w_off, weight, wofb, wtb);
  transpose_x<<<dim3(NPIX / 64), dim3(256), 0, stream>>>(x, xt);
  offset_mfma<<<dim3(NPIX / 64), dim3(256), 0, stream>>>(xt, wofb, b_off,
                                                         offset);
  dcn_main<<<dim3(NPIX / 64), dim3(256), 0, stream>>>(xt, offset, wtb, out);
}